// Round 17
// baseline (190.348 us; speedup 1.0000x reference)
//
#include <hip/hip_runtime.h>

// GCN decoder: z2 = A( relu(A(x)@W1 + b1) )@W2 + b2,  A = D^-1/2 (Adj+I) D^-1/2
// f16 numerics, CSR via bucketed counting sort, width-128 aggregation.
// Round 17: column-blocked (quarter-split) gather tables. x/agg/h2 stored as
// 4 planes of [N64][32] f16 (3.2 MB each -> fits 4 MB per-XCD L2). Aggs run
// grid (nodeblocks, 4): all CUs sweep one quarter at a time -> gathers are
// L2-resident. 8-lane groups, f16x4/lane, 8 rows in flight per group.

constexpr int F = 128;    // aggregation width
constexpr int HID = 256;  // hidden width
constexpr int ECHUNK = 8192;  // edges per binning block

typedef __attribute__((ext_vector_type(8))) _Float16 f16x8;
typedef __attribute__((ext_vector_type(4))) _Float16 f16x4;
typedef __attribute__((ext_vector_type(4))) float f32x4;

// fused prep: blocks [0,nbC) = per-chunk dst-bucket histogram -> bhist;
// [nbC,nbC+128) W1->w1t; [nbC+128,nbC+256) W2->w2t; rest x->xq (quarter planes)
__global__ __launch_bounds__(256) void k_prep(const int* __restrict__ dst,
                                              unsigned* __restrict__ bhist,
                                              const float* __restrict__ W1,
                                              const float* __restrict__ W2,
                                              const float* __restrict__ x,
                                              _Float16* __restrict__ w1t,
                                              _Float16* __restrict__ w2t,
                                              _Float16* __restrict__ xq,
                                              size_t pstride,
                                              int E, int nbC, int n4) {
  __shared__ unsigned hist[256];
  int b = blockIdx.x;
  int tid = threadIdx.x;
  if (b < nbC) {  // binning histogram
    hist[tid] = 0u;
    __syncthreads();
    int i0 = b * ECHUNK;
    int i1 = min(i0 + ECHUNK, E);
    for (int i = i0 + tid; i < i1; i += 256)
      atomicAdd(&hist[((unsigned)dst[i]) >> 8], 1u);
    __syncthreads();
    bhist[b * 256 + tid] = hist[tid];
  } else if (b < nbC + 128) {  // W1 [F][HID] -> w1t [HID][F]
    int idx = (b - nbC) * 256 + tid;
    int k = idx / HID, n = idx - k * HID;
    w1t[n * F + k] = (_Float16)W1[idx];
  } else if (b < nbC + 256) {  // W2 [HID][F] -> w2t [F][HID]
    int idx = (b - nbC - 128) * 256 + tid;
    int k = idx / F, n = idx - k * F;
    w2t[n * HID + k] = (_Float16)W2[idx];
  } else {  // x fp32 -> f16 quarter planes
    int i = (b - nbC - 256) * 256 + tid;
    if (i < n4) {
      float4 v = ((const float4*)x)[i];
      int nd = i >> 5;            // 32 float4 per row
      int c4 = (i & 31) * 4;      // starting col
      int plane = c4 >> 5;
      int incol = c4 & 31;
      f16x4 o;
      o.x = (_Float16)v.x; o.y = (_Float16)v.y;
      o.z = (_Float16)v.z; o.w = (_Float16)v.w;
      *(f16x4*)&xq[(size_t)plane * pstride + (size_t)nd * 32 + incol] = o;
    }
  }
}

// reduce bhist columns -> bucket counts; exclusive scan -> bbase[P+1], bcur;
// rowptr[N]=E
__global__ __launch_bounds__(256) void k_bscan(const unsigned* __restrict__ bhist,
                                               int nbC,
                                               unsigned* __restrict__ bbase,
                                               unsigned* __restrict__ bcur,
                                               int* __restrict__ rowptr,
                                               int P, int N, int E) {
  __shared__ unsigned wsum[4];
  int tid = threadIdx.x;
  unsigned v = 0u;
  for (int c = 0; c < nbC; ++c) v += bhist[c * 256 + tid];
  if (tid >= P) v = 0u;
  unsigned sv = v;
#pragma unroll
  for (int off = 1; off < 64; off <<= 1) {
    unsigned t = __shfl_up(sv, off);
    if ((tid & 63) >= off) sv += t;
  }
  int w = tid >> 6;
  if ((tid & 63) == 63) wsum[w] = sv;
  __syncthreads();
  unsigned wpre = 0;
  for (int k = 0; k < w; ++k) wpre += wsum[k];
  unsigned excl = wpre + sv - v;
  if (tid < P) {
    bbase[tid] = excl;
    bcur[tid] = excl;
  }
  if (tid == P - 1) bbase[P] = excl + v;
  if (tid == 0) rowptr[N] = E;
}

// binning pass 2: reserve ranges using precomputed per-block hist, write packed
// packed = src | (dst&255)<<16
__global__ __launch_bounds__(256) void k_binscat(const int* __restrict__ src,
                                                 const int* __restrict__ dst,
                                                 const unsigned* __restrict__ bhist,
                                                 unsigned* __restrict__ bcur,
                                                 unsigned* __restrict__ packed, int E) {
  __shared__ unsigned hist[256];
  __shared__ unsigned basel[256];
  int tid = threadIdx.x;
  unsigned c = bhist[blockIdx.x * 256 + tid];
  if (c) basel[tid] = atomicAdd(&bcur[tid], c);
  hist[tid] = 0u;
  __syncthreads();
  int i0 = blockIdx.x * ECHUNK;
  int i1 = min(i0 + ECHUNK, E);
  for (int i = i0 + tid; i < i1; i += 256) {
    unsigned d = (unsigned)dst[i];
    unsigned b = d >> 8;
    unsigned pos = basel[b] + atomicAdd(&hist[b], 1u);
    packed[pos] = ((unsigned)src[i]) | ((d & 255u) << 16);
  }
}

// per-bucket CSR finalize: dinv + rowptr (coalesced), esrc u16 (LDS-cursor scatter)
__global__ __launch_bounds__(256) void k_bcsr(const unsigned* __restrict__ packed,
                                              const unsigned* __restrict__ bbase,
                                              float* __restrict__ dinv,
                                              int* __restrict__ rowptr,
                                              unsigned short* __restrict__ esrc,
                                              int N) {
  __shared__ unsigned hist[256];
  __shared__ unsigned rowloc[256];
  __shared__ unsigned cur[256];
  __shared__ unsigned wsum[4];
  int tid = threadIdx.x, b = blockIdx.x;
  int e0 = (int)bbase[b], e1 = (int)bbase[b + 1];
  hist[tid] = 0u;
  __syncthreads();
  for (int i = e0 + tid; i < e1; i += 256)
    atomicAdd(&hist[packed[i] >> 16], 1u);
  __syncthreads();
  unsigned v = hist[tid];
  unsigned sv = v;
#pragma unroll
  for (int off = 1; off < 64; off <<= 1) {
    unsigned t = __shfl_up(sv, off);
    if ((tid & 63) >= off) sv += t;
  }
  int w = tid >> 6;
  if ((tid & 63) == 63) wsum[w] = sv;
  __syncthreads();
  unsigned wpre = 0;
  for (int k = 0; k < w; ++k) wpre += wsum[k];
  unsigned excl = wpre + sv - v;
  int node = b * 256 + tid;
  if (node < N) {
    dinv[node] = rsqrtf((float)v + 1.0f);  // +1 = self-loop
    rowptr[node] = e0 + (int)excl;
  }
  rowloc[tid] = (unsigned)e0 + excl;
  cur[tid] = 0u;
  __syncthreads();
  for (int i = e0 + tid; i < e1; i += 256) {
    unsigned pk = packed[i];
    unsigned dl = pk >> 16;
    unsigned pos = rowloc[dl] + atomicAdd(&cur[dl], 1u);
    esrc[pos] = (unsigned short)(pk & 0xffffu);
  }
}

// Quarter-plane aggregation: grid (nodeblocks, 4). 8-lane group per node,
// f16x4/lane = 64B plane-row per group request; 8 rows in flight per group.
// OUTF=0: write f16 quarter plane (layer 1). OUTF=1: +bias, fp32 out (layer 2).
template <int OUTF>
__global__ __launch_bounds__(256) void k_aggq(const int* __restrict__ rowptr,
                                              const unsigned short* __restrict__ esrc,
                                              const float* __restrict__ dinv,
                                              const _Float16* __restrict__ tblq,
                                              size_t pstride,
                                              _Float16* __restrict__ outq,
                                              const float* __restrict__ bias,
                                              float* __restrict__ outf, int N) {
  int q = blockIdx.y;
  const _Float16* tbl = tblq + (size_t)q * pstride;
  int node = blockIdx.x * 32 + (threadIdx.x >> 3);
  int li = threadIdx.x & 7;
  int lanebase = (threadIdx.x & 63) & 56;  // group base within wave
  if (node >= N) return;
  float di = dinv[node];
  float w0 = di * di;
  f16x4 svv = ((const f16x4*)(tbl + (size_t)node * 32))[li];
  float acc[4] = {};
  int beg = rowptr[node], end = rowptr[node + 1];
  for (int b = beg; b < end; b += 8) {
    int n = min(8, end - b);
    int s = 0;
    float w = 0.f;
    if (li < n) {
      s = (int)esrc[b + li];
      w = dinv[s] * di;
    }
    if (n == 8) {
      int ss[8];
      float wz[8];
#pragma unroll
      for (int j = 0; j < 8; ++j) {
        ss[j] = __shfl(s, lanebase + j);
        wz[j] = __shfl(w, lanebase + j);
      }
      f16x4 vv[8];
#pragma unroll
      for (int j = 0; j < 8; ++j)
        vv[j] = ((const f16x4*)(tbl + (size_t)ss[j] * 32))[li];
#pragma unroll
      for (int j = 0; j < 8; ++j)
#pragma unroll
        for (int k = 0; k < 4; ++k)
          acc[k] += (float)vv[j][k] * wz[j];
    } else {
      for (int t = 0; t < n; ++t) {
        int s0 = __shfl(s, lanebase + t);
        float wa = __shfl(w, lanebase + t);
        f16x4 v0 = ((const f16x4*)(tbl + (size_t)s0 * 32))[li];
#pragma unroll
        for (int k = 0; k < 4; ++k) acc[k] += (float)v0[k] * wa;
      }
    }
  }
  if (OUTF == 0) {
    f16x4 ov;
#pragma unroll
    for (int k = 0; k < 4; ++k)
      ov[k] = (_Float16)(acc[k] + (float)svv[k] * w0);
    ((f16x4*)(outq + (size_t)q * pstride + (size_t)node * 32))[li] = ov;
  } else {
    float4 bb = ((const float4*)(bias + q * 32))[li];
    float4 o;
    o.x = acc[0] + (float)svv[0] * w0 + bb.x;
    o.y = acc[1] + (float)svv[1] * w0 + bb.y;
    o.z = acc[2] + (float)svv[2] * w0 + bb.z;
    o.w = acc[3] + (float)svv[3] * w0 + bb.w;
    *(float4*)(outf + (size_t)node * F + q * 32 + li * 4) = o;
  }
}

// Fused GEMM1+GEMM2 per 64-row tile (A and H2 in quarter-plane layout):
//   z1 = relu(A[64,128] @ W1t[256,128]^T + b1)   -> LDS only
//   h2 = z1[64,256] @ W2t[128,256]^T             -> quarter planes
// H2 may alias A (block reads its rows before writing them).
__global__ __launch_bounds__(256) void k_fgemm(const _Float16* __restrict__ Aq,
                                               size_t pstride,
                                               const _Float16* __restrict__ B1,
                                               const float* __restrict__ bias,
                                               const _Float16* __restrict__ B2,
                                               _Float16* __restrict__ H2q, int M) {
  __shared__ _Float16 AL[64 * 128];   // 16 KB
  __shared__ _Float16 ZL[64 * 256];   // 32 KB
  int tid = threadIdx.x;
  int lane = tid & 63, wid = tid >> 6;
  int row0 = blockIdx.x * 64;

  // stage A from quarter planes (swizzled LDS)
#pragma unroll
  for (int i = 0; i < 4; ++i) {
    int g = i * 256 + tid;
    int r = g >> 4, gi = g & 15;
    int o = r * 128 + ((gi ^ (r & 7)) * 8);
    int plane = gi >> 2;
    int incol = (gi & 3) * 8;
    *(f16x8*)&AL[o] = *(const f16x8*)&Aq[(size_t)plane * pstride +
                                         (size_t)(row0 + r) * 32 + incol];
  }
  __syncthreads();

  // GEMM1: 64x256, 4 waves x 64 cols
  f32x4 acc[4][4] = {};
#pragma unroll
  for (int ks = 0; ks < 4; ++ks) {
    f16x8 ah[4], bh[4];
#pragma unroll
    for (int mf = 0; mf < 4; ++mf) {
      int r = mf * 16 + (lane & 15);
      int g = ks * 4 + (lane >> 4);
      ah[mf] = *(const f16x8*)&AL[r * 128 + ((g ^ (r & 7)) * 8)];
    }
#pragma unroll
    for (int nf = 0; nf < 4; ++nf) {
      int c = wid * 64 + nf * 16 + (lane & 15);
      bh[nf] = *(const f16x8*)&B1[(size_t)c * 128 + ks * 32 + (lane >> 4) * 8];
    }
#pragma unroll
    for (int mf = 0; mf < 4; ++mf)
#pragma unroll
      for (int nf = 0; nf < 4; ++nf)
        acc[mf][nf] = __builtin_amdgcn_mfma_f32_16x16x32_f16(
            ah[mf], bh[nf], acc[mf][nf], 0, 0, 0);
  }

  // epilogue 1: relu(acc+bias) -> ZL (swizzled)
#pragma unroll
  for (int mf = 0; mf < 4; ++mf) {
    int r0l = mf * 16 + (lane >> 4) * 4;
#pragma unroll
    for (int nf = 0; nf < 4; ++nf) {
      int c = wid * 64 + nf * 16 + (lane & 15);
      float bv = bias[c];
      int gi = c >> 3, ci = c & 7;
#pragma unroll
      for (int r = 0; r < 4; ++r) {
        int rr = r0l + r;
        float v = fmaxf(acc[mf][nf][r] + bv, 0.f);
        ZL[rr * 256 + ((gi ^ (rr & 7)) * 8) + ci] = (_Float16)v;
      }
    }
  }
  __syncthreads();

  // GEMM2: 64x128, 4 waves x 32 cols, K=256 from ZL
  f32x4 acc2[4][2] = {};
#pragma unroll
  for (int ks = 0; ks < 8; ++ks) {
    f16x8 ah[4], bh[2];
#pragma unroll
    for (int mf = 0; mf < 4; ++mf) {
      int r = mf * 16 + (lane & 15);
      int g = ks * 4 + (lane >> 4);
      ah[mf] = *(const f16x8*)&ZL[r * 256 + ((g ^ (r & 7)) * 8)];
    }
#pragma unroll
    for (int nf = 0; nf < 2; ++nf) {
      int c = wid * 32 + nf * 16 + (lane & 15);
      bh[nf] = *(const f16x8*)&B2[(size_t)c * 256 + ks * 32 + (lane >> 4) * 8];
    }
#pragma unroll
    for (int mf = 0; mf < 4; ++mf)
#pragma unroll
      for (int nf = 0; nf < 2; ++nf)
        acc2[mf][nf] = __builtin_amdgcn_mfma_f32_16x16x32_f16(
            ah[mf], bh[nf], acc2[mf][nf], 0, 0, 0);
  }

  // h2 write into quarter plane `wid` (c = wid*32 + nf*16 + lane&15)
#pragma unroll
  for (int mf = 0; mf < 4; ++mf) {
    int r0 = row0 + mf * 16 + (lane >> 4) * 4;
#pragma unroll
    for (int nf = 0; nf < 2; ++nf) {
      int ic = nf * 16 + (lane & 15);
#pragma unroll
      for (int r = 0; r < 4; ++r)
        H2q[(size_t)wid * pstride + (size_t)(r0 + r) * 32 + ic] =
            (_Float16)acc2[mf][nf][r];
    }
  }
}

extern "C" void kernel_launch(void* const* d_in, const int* in_sizes, int n_in,
                              void* d_out, int out_size, void* d_ws, size_t ws_size,
                              hipStream_t stream) {
  const float* x = (const float*)d_in[0];
  const int* ei = (const int*)d_in[1];
  const float* W1 = (const float*)d_in[2];
  const float* b1 = (const float*)d_in[3];
  const float* W2 = (const float*)d_in[4];
  const float* b2 = (const float*)d_in[5];
  float* out = (float*)d_out;

  int N = in_sizes[0] / F;  // 50000
  int E = in_sizes[1] / 2;  // 800000
  const int* src = ei;
  const int* dst = ei + E;
  int P = (N + 255) / 256;  // dst buckets of 256 nodes (N < 65536)
  int nbC = (E + ECHUNK - 1) / ECHUNK;
  int N64 = (N + 63) & ~63;           // padded rows for 64-row GEMM tiles
  size_t pstride = (size_t)N64 * 32;  // f16 elems per quarter plane

  // workspace layout (byte-based, 256B aligned chunks)
  char* ws = (char*)d_ws;
  size_t off = 0;
  auto allocB = [&](size_t bytes) {
    void* p = ws + off;
    off += ((bytes + 255) & ~(size_t)255);
    return p;
  };
  float* dinv = (float*)allocB((size_t)N * 4);
  int* rowptr = (int*)allocB(((size_t)N + 1) * 4);
  unsigned* bbase = (unsigned*)allocB(257 * 4);
  unsigned* bcur = (unsigned*)allocB(256 * 4);
  unsigned* bhist = (unsigned*)allocB((size_t)nbC * 256 * 4);
  unsigned* packed = (unsigned*)allocB((size_t)E * 4);
  unsigned short* esrc = (unsigned short*)allocB((size_t)E * 2);
  _Float16* xq = (_Float16*)allocB(4 * pstride * 2);   // x quarter planes
  _Float16* aggq = (_Float16*)allocB(4 * pstride * 2); // agg quarter planes
  _Float16* w1t = (_Float16*)allocB((size_t)F * HID * 2);
  _Float16* w2t = (_Float16*)allocB((size_t)HID * F * 2);
  // h2 aliases aggq (fused GEMM reads its rows before writing them)
  _Float16* h2q = aggq;

  int n4 = N * F / 4;
  int nbPrep = nbC + 256 + (n4 + 255) / 256;

  k_prep<<<nbPrep, 256, 0, stream>>>(dst, bhist, W1, W2, x, w1t, w2t, xq,
                                     pstride, E, nbC, n4);
  k_bscan<<<1, 256, 0, stream>>>(bhist, nbC, bbase, bcur, rowptr, P, N, E);
  k_binscat<<<nbC, 256, 0, stream>>>(src, dst, bhist, bcur, packed, E);
  k_bcsr<<<P, 256, 0, stream>>>(packed, bbase, dinv, rowptr, esrc, N);

  dim3 gAgg((N + 31) / 32, 4);
  int mb = (N + 63) / 64;

  // layer 1 gather (quarter-swept), fused GEMM1+GEMM2, layer 2 gather
  k_aggq<0><<<gAgg, 256, 0, stream>>>(rowptr, esrc, dinv, xq, pstride,
                                      aggq, nullptr, nullptr, N);
  k_fgemm<<<mb, 256, 0, stream>>>(aggq, pstride, w1t, b1, w2t, h2q, N);
  k_aggq<1><<<gAgg, 256, 0, stream>>>(rowptr, esrc, dinv, h2q, pstride,
                                      nullptr, b2, out, N);
}

// Round 18
// 158.828 us; speedup vs baseline: 1.1985x; 1.1985x over previous
//
#include <hip/hip_runtime.h>

// GCN decoder: z2 = A( relu(A(x)@W1 + b1) )@W2 + b2,  A = D^-1/2 (Adj+I) D^-1/2
// f16 numerics end-to-end, CSR via bucketed counting sort, width-128 aggregation.
// Round 18: revert to round-16 structure (best: 158.95us). Unified group-gather
// aggs; fused GEMM1+GEMM2 (z1 in LDS); ushort esrc; bucketed counting-sort CSR.

constexpr int F = 128;    // aggregation width
constexpr int HID = 256;  // hidden width
constexpr int ECHUNK = 8192;  // edges per binning block

typedef __attribute__((ext_vector_type(8))) _Float16 f16x8;
typedef __attribute__((ext_vector_type(4))) _Float16 f16x4;
typedef __attribute__((ext_vector_type(4))) float f32x4;

// fused prep: blocks [0,nbC) = per-chunk dst-bucket histogram -> bhist;
// [nbC,nbC+128) W1->w1t; [nbC+128,nbC+256) W2->w2t; rest x->xh
__global__ __launch_bounds__(256) void k_prep(const int* __restrict__ dst,
                                              unsigned* __restrict__ bhist,
                                              const float* __restrict__ W1,
                                              const float* __restrict__ W2,
                                              const float* __restrict__ x,
                                              _Float16* __restrict__ w1t,
                                              _Float16* __restrict__ w2t,
                                              _Float16* __restrict__ xh,
                                              int E, int nbC, int n4) {
  __shared__ unsigned hist[256];
  int b = blockIdx.x;
  int tid = threadIdx.x;
  if (b < nbC) {  // binning histogram
    hist[tid] = 0u;
    __syncthreads();
    int i0 = b * ECHUNK;
    int i1 = min(i0 + ECHUNK, E);
    for (int i = i0 + tid; i < i1; i += 256)
      atomicAdd(&hist[((unsigned)dst[i]) >> 8], 1u);
    __syncthreads();
    bhist[b * 256 + tid] = hist[tid];
  } else if (b < nbC + 128) {  // W1 [F][HID] -> w1t [HID][F]
    int idx = (b - nbC) * 256 + tid;
    int k = idx / HID, n = idx - k * HID;
    w1t[n * F + k] = (_Float16)W1[idx];
  } else if (b < nbC + 256) {  // W2 [HID][F] -> w2t [F][HID]
    int idx = (b - nbC - 128) * 256 + tid;
    int k = idx / F, n = idx - k * F;
    w2t[n * HID + k] = (_Float16)W2[idx];
  } else {  // x fp32 -> f16 plane
    int i = (b - nbC - 256) * 256 + tid;
    if (i < n4) {
      float4 v = ((const float4*)x)[i];
      f16x4 o;
      o.x = (_Float16)v.x; o.y = (_Float16)v.y;
      o.z = (_Float16)v.z; o.w = (_Float16)v.w;
      ((f16x4*)xh)[i] = o;
    }
  }
}

// reduce bhist columns -> bucket counts; exclusive scan -> bbase[P+1], bcur;
// rowptr[N]=E
__global__ __launch_bounds__(256) void k_bscan(const unsigned* __restrict__ bhist,
                                               int nbC,
                                               unsigned* __restrict__ bbase,
                                               unsigned* __restrict__ bcur,
                                               int* __restrict__ rowptr,
                                               int P, int N, int E) {
  __shared__ unsigned wsum[4];
  int tid = threadIdx.x;
  unsigned v = 0u;
  for (int c = 0; c < nbC; ++c) v += bhist[c * 256 + tid];
  if (tid >= P) v = 0u;
  unsigned sv = v;
#pragma unroll
  for (int off = 1; off < 64; off <<= 1) {
    unsigned t = __shfl_up(sv, off);
    if ((tid & 63) >= off) sv += t;
  }
  int w = tid >> 6;
  if ((tid & 63) == 63) wsum[w] = sv;
  __syncthreads();
  unsigned wpre = 0;
  for (int k = 0; k < w; ++k) wpre += wsum[k];
  unsigned excl = wpre + sv - v;
  if (tid < P) {
    bbase[tid] = excl;
    bcur[tid] = excl;
  }
  if (tid == P - 1) bbase[P] = excl + v;
  if (tid == 0) rowptr[N] = E;
}

// binning pass 2: reserve ranges using precomputed per-block hist, write packed
// packed = src | (dst&255)<<16
__global__ __launch_bounds__(256) void k_binscat(const int* __restrict__ src,
                                                 const int* __restrict__ dst,
                                                 const unsigned* __restrict__ bhist,
                                                 unsigned* __restrict__ bcur,
                                                 unsigned* __restrict__ packed, int E) {
  __shared__ unsigned hist[256];
  __shared__ unsigned basel[256];
  int tid = threadIdx.x;
  unsigned c = bhist[blockIdx.x * 256 + tid];
  if (c) basel[tid] = atomicAdd(&bcur[tid], c);
  hist[tid] = 0u;
  __syncthreads();
  int i0 = blockIdx.x * ECHUNK;
  int i1 = min(i0 + ECHUNK, E);
  for (int i = i0 + tid; i < i1; i += 256) {
    unsigned d = (unsigned)dst[i];
    unsigned b = d >> 8;
    unsigned pos = basel[b] + atomicAdd(&hist[b], 1u);
    packed[pos] = ((unsigned)src[i]) | ((d & 255u) << 16);
  }
}

// per-bucket CSR finalize: dinv + rowptr (coalesced), esrc u16 (LDS-cursor scatter)
__global__ __launch_bounds__(256) void k_bcsr(const unsigned* __restrict__ packed,
                                              const unsigned* __restrict__ bbase,
                                              float* __restrict__ dinv,
                                              int* __restrict__ rowptr,
                                              unsigned short* __restrict__ esrc,
                                              int N) {
  __shared__ unsigned hist[256];
  __shared__ unsigned rowloc[256];
  __shared__ unsigned cur[256];
  __shared__ unsigned wsum[4];
  int tid = threadIdx.x, b = blockIdx.x;
  int e0 = (int)bbase[b], e1 = (int)bbase[b + 1];
  hist[tid] = 0u;
  __syncthreads();
  for (int i = e0 + tid; i < e1; i += 256)
    atomicAdd(&hist[packed[i] >> 16], 1u);
  __syncthreads();
  unsigned v = hist[tid];
  unsigned sv = v;
#pragma unroll
  for (int off = 1; off < 64; off <<= 1) {
    unsigned t = __shfl_up(sv, off);
    if ((tid & 63) >= off) sv += t;
  }
  int w = tid >> 6;
  if ((tid & 63) == 63) wsum[w] = sv;
  __syncthreads();
  unsigned wpre = 0;
  for (int k = 0; k < w; ++k) wpre += wsum[k];
  unsigned excl = wpre + sv - v;
  int node = b * 256 + tid;
  if (node < N) {
    dinv[node] = rsqrtf((float)v + 1.0f);  // +1 = self-loop
    rowptr[node] = e0 + (int)excl;
  }
  rowloc[tid] = (unsigned)e0 + excl;
  cur[tid] = 0u;
  __syncthreads();
  for (int i = e0 + tid; i < e1; i += 256) {
    unsigned pk = packed[i];
    unsigned dl = pk >> 16;
    unsigned pos = rowloc[dl] + atomicAdd(&cur[dl], 1u);
    esrc[pos] = (unsigned short)(pk & 0xffffu);
  }
}

// Layer-1 agg: 16-lane group per node (4 nodes/wave). Lane li holds f16x8
// (features 8*li..8*li+7); a group's load = one coalesced 256B row request.
__global__ __launch_bounds__(256) void k_agg1(const int* __restrict__ rowptr,
                                              const unsigned short* __restrict__ esrc,
                                              const float* __restrict__ dinv,
                                              const _Float16* __restrict__ xh,
                                              _Float16* __restrict__ outp, int N) {
  int node = blockIdx.x * 16 + (threadIdx.x >> 4);
  int li = threadIdx.x & 15;
  int lanebase = (threadIdx.x & 63) & 48;  // group base within wave
  if (node >= N) return;
  float di = dinv[node];
  float w0 = di * di;
  f16x8 svv = ((const f16x8*)(xh + (size_t)node * F))[li];
  float acc[8] = {};
  int beg = rowptr[node], end = rowptr[node + 1];
  for (int b = beg; b < end; b += 16) {
    int n = min(16, end - b);
    int s = 0;
    float w = 0.f;
    if (li < n) {
      s = (int)esrc[b + li];
      w = dinv[s] * di;
    }
    int t = 0;
    for (; t + 7 < n; t += 8) {
      int ss[8];
      float wz[8];
#pragma unroll
      for (int j = 0; j < 8; ++j) {
        ss[j] = __shfl(s, lanebase + t + j);
        wz[j] = __shfl(w, lanebase + t + j);
      }
      f16x8 vv[8];
#pragma unroll
      for (int j = 0; j < 8; ++j)
        vv[j] = ((const f16x8*)(xh + (size_t)ss[j] * F))[li];
#pragma unroll
      for (int j = 0; j < 8; ++j)
#pragma unroll
        for (int k = 0; k < 8; ++k)
          acc[k] += (float)vv[j][k] * wz[j];
    }
    for (; t + 3 < n; t += 4) {
      int ss[4];
      float wz[4];
#pragma unroll
      for (int j = 0; j < 4; ++j) {
        ss[j] = __shfl(s, lanebase + t + j);
        wz[j] = __shfl(w, lanebase + t + j);
      }
      f16x8 vv[4];
#pragma unroll
      for (int j = 0; j < 4; ++j)
        vv[j] = ((const f16x8*)(xh + (size_t)ss[j] * F))[li];
#pragma unroll
      for (int j = 0; j < 4; ++j)
#pragma unroll
        for (int k = 0; k < 8; ++k)
          acc[k] += (float)vv[j][k] * wz[j];
    }
    for (; t < n; ++t) {
      int s0 = __shfl(s, lanebase + t);
      float wa = __shfl(w, lanebase + t);
      f16x8 v0 = ((const f16x8*)(xh + (size_t)s0 * F))[li];
#pragma unroll
      for (int k = 0; k < 8; ++k) acc[k] += (float)v0[k] * wa;
    }
  }
  f16x8 ov;
#pragma unroll
  for (int k = 0; k < 8; ++k) ov[k] = (_Float16)(acc[k] + (float)svv[k] * w0);
  ((f16x8*)(outp + (size_t)node * F))[li] = ov;
}

// Layer-2 agg: same structure, + bias, fp32 output (final)
__global__ __launch_bounds__(256) void k_agg_out(const int* __restrict__ rowptr,
                                                 const unsigned short* __restrict__ esrc,
                                                 const float* __restrict__ dinv,
                                                 const _Float16* __restrict__ hb,
                                                 const float* __restrict__ bias,
                                                 float* __restrict__ outp, int N) {
  int node = blockIdx.x * 16 + (threadIdx.x >> 4);
  int li = threadIdx.x & 15;
  int lanebase = (threadIdx.x & 63) & 48;
  if (node >= N) return;
  float di = dinv[node];
  float w0 = di * di;
  f16x8 svv = ((const f16x8*)(hb + (size_t)node * F))[li];
  float acc[8] = {};
  int beg = rowptr[node], end = rowptr[node + 1];
  for (int b = beg; b < end; b += 16) {
    int n = min(16, end - b);
    int s = 0;
    float w = 0.f;
    if (li < n) {
      s = (int)esrc[b + li];
      w = dinv[s] * di;
    }
    int t = 0;
    for (; t + 7 < n; t += 8) {
      int ss[8];
      float wz[8];
#pragma unroll
      for (int j = 0; j < 8; ++j) {
        ss[j] = __shfl(s, lanebase + t + j);
        wz[j] = __shfl(w, lanebase + t + j);
      }
      f16x8 vv[8];
#pragma unroll
      for (int j = 0; j < 8; ++j)
        vv[j] = ((const f16x8*)(hb + (size_t)ss[j] * F))[li];
#pragma unroll
      for (int j = 0; j < 8; ++j)
#pragma unroll
        for (int k = 0; k < 8; ++k)
          acc[k] += (float)vv[j][k] * wz[j];
    }
    for (; t + 3 < n; t += 4) {
      int ss[4];
      float wz[4];
#pragma unroll
      for (int j = 0; j < 4; ++j) {
        ss[j] = __shfl(s, lanebase + t + j);
        wz[j] = __shfl(w, lanebase + t + j);
      }
      f16x8 vv[4];
#pragma unroll
      for (int j = 0; j < 4; ++j)
        vv[j] = ((const f16x8*)(hb + (size_t)ss[j] * F))[li];
#pragma unroll
      for (int j = 0; j < 4; ++j)
#pragma unroll
        for (int k = 0; k < 8; ++k)
          acc[k] += (float)vv[j][k] * wz[j];
    }
    for (; t < n; ++t) {
      int s0 = __shfl(s, lanebase + t);
      float wa = __shfl(w, lanebase + t);
      f16x8 v0 = ((const f16x8*)(hb + (size_t)s0 * F))[li];
#pragma unroll
      for (int k = 0; k < 8; ++k) acc[k] += (float)v0[k] * wa;
    }
  }
  float4 bb0 = ((const float4*)bias)[li * 2];
  float4 bb1 = ((const float4*)bias)[li * 2 + 1];
  float4 o0, o1;
  o0.x = acc[0] + (float)svv[0] * w0 + bb0.x;
  o0.y = acc[1] + (float)svv[1] * w0 + bb0.y;
  o0.z = acc[2] + (float)svv[2] * w0 + bb0.z;
  o0.w = acc[3] + (float)svv[3] * w0 + bb0.w;
  o1.x = acc[4] + (float)svv[4] * w0 + bb1.x;
  o1.y = acc[5] + (float)svv[5] * w0 + bb1.y;
  o1.z = acc[6] + (float)svv[6] * w0 + bb1.z;
  o1.w = acc[7] + (float)svv[7] * w0 + bb1.w;
  float* orow = outp + (size_t)node * F + li * 8;
  *(float4*)orow = o0;
  *(float4*)(orow + 4) = o1;
}

// Fused GEMM1+GEMM2 per 64-row tile:
//   z1 = relu(A[64,128] @ W1t[256,128]^T + b1)   -> LDS only (never HBM)
//   h2 = z1[64,256] @ W2t[128,256]^T             -> global f16
// h2 may alias A: each block reads only its own rows (staged before write).
__global__ __launch_bounds__(256) void k_fgemm(const _Float16* __restrict__ A,
                                               const _Float16* __restrict__ B1,
                                               const float* __restrict__ bias,
                                               const _Float16* __restrict__ B2,
                                               _Float16* __restrict__ H2, int M) {
  __shared__ _Float16 AL[64 * 128];   // 16 KB
  __shared__ _Float16 ZL[64 * 256];   // 32 KB
  int tid = threadIdx.x;
  int lane = tid & 63, wid = tid >> 6;
  int row0 = blockIdx.x * 64;

  // stage A (swizzled)
#pragma unroll
  for (int i = 0; i < 4; ++i) {
    int g = i * 256 + tid;
    int r = g >> 4, gi = g & 15;
    int o = r * 128 + ((gi ^ (r & 7)) * 8);
    size_t go = (size_t)(row0 + r) * 128 + gi * 8;
    *(f16x8*)&AL[o] = *(const f16x8*)&A[go];
  }
  __syncthreads();

  // GEMM1: 64x256, 4 waves x 64 cols
  f32x4 acc[4][4] = {};
#pragma unroll
  for (int ks = 0; ks < 4; ++ks) {
    f16x8 ah[4], bh[4];
#pragma unroll
    for (int mf = 0; mf < 4; ++mf) {
      int r = mf * 16 + (lane & 15);
      int g = ks * 4 + (lane >> 4);
      ah[mf] = *(const f16x8*)&AL[r * 128 + ((g ^ (r & 7)) * 8)];
    }
#pragma unroll
    for (int nf = 0; nf < 4; ++nf) {
      int c = wid * 64 + nf * 16 + (lane & 15);
      bh[nf] = *(const f16x8*)&B1[(size_t)c * 128 + ks * 32 + (lane >> 4) * 8];
    }
#pragma unroll
    for (int mf = 0; mf < 4; ++mf)
#pragma unroll
      for (int nf = 0; nf < 4; ++nf)
        acc[mf][nf] = __builtin_amdgcn_mfma_f32_16x16x32_f16(
            ah[mf], bh[nf], acc[mf][nf], 0, 0, 0);
  }

  // epilogue 1: relu(acc+bias) -> ZL (swizzled for GEMM2 A-reads)
#pragma unroll
  for (int mf = 0; mf < 4; ++mf) {
    int r0l = mf * 16 + (lane >> 4) * 4;
#pragma unroll
    for (int nf = 0; nf < 4; ++nf) {
      int c = wid * 64 + nf * 16 + (lane & 15);
      float bv = bias[c];
      int gi = c >> 3, ci = c & 7;
#pragma unroll
      for (int r = 0; r < 4; ++r) {
        int rr = r0l + r;
        float v = fmaxf(acc[mf][nf][r] + bv, 0.f);
        ZL[rr * 256 + ((gi ^ (rr & 7)) * 8) + ci] = (_Float16)v;
      }
    }
  }
  __syncthreads();

  // GEMM2: 64x128, 4 waves x 32 cols, K=256 from ZL
  f32x4 acc2[4][2] = {};
#pragma unroll
  for (int ks = 0; ks < 8; ++ks) {
    f16x8 ah[4], bh[2];
#pragma unroll
    for (int mf = 0; mf < 4; ++mf) {
      int r = mf * 16 + (lane & 15);
      int g = ks * 4 + (lane >> 4);
      ah[mf] = *(const f16x8*)&ZL[r * 256 + ((g ^ (r & 7)) * 8)];
    }
#pragma unroll
    for (int nf = 0; nf < 2; ++nf) {
      int c = wid * 32 + nf * 16 + (lane & 15);
      bh[nf] = *(const f16x8*)&B2[(size_t)c * 256 + ks * 32 + (lane >> 4) * 8];
    }
#pragma unroll
    for (int mf = 0; mf < 4; ++mf)
#pragma unroll
      for (int nf = 0; nf < 2; ++nf)
        acc2[mf][nf] = __builtin_amdgcn_mfma_f32_16x16x32_f16(
            ah[mf], bh[nf], acc2[mf][nf], 0, 0, 0);
  }

  // h2 write (pad rows exist -> no M check needed on stores within tile)
#pragma unroll
  for (int mf = 0; mf < 4; ++mf) {
    int r0 = row0 + mf * 16 + (lane >> 4) * 4;
#pragma unroll
    for (int nf = 0; nf < 2; ++nf) {
      int c = wid * 32 + nf * 16 + (lane & 15);
#pragma unroll
      for (int r = 0; r < 4; ++r)
        H2[(size_t)(r0 + r) * F + c] = (_Float16)acc2[mf][nf][r];
    }
  }
}

extern "C" void kernel_launch(void* const* d_in, const int* in_sizes, int n_in,
                              void* d_out, int out_size, void* d_ws, size_t ws_size,
                              hipStream_t stream) {
  const float* x = (const float*)d_in[0];
  const int* ei = (const int*)d_in[1];
  const float* W1 = (const float*)d_in[2];
  const float* b1 = (const float*)d_in[3];
  const float* W2 = (const float*)d_in[4];
  const float* b2 = (const float*)d_in[5];
  float* out = (float*)d_out;

  int N = in_sizes[0] / F;  // 50000
  int E = in_sizes[1] / 2;  // 800000
  const int* src = ei;
  const int* dst = ei + E;
  int P = (N + 255) / 256;  // dst buckets of 256 nodes (N < 65536)
  int nbC = (E + ECHUNK - 1) / ECHUNK;

  // workspace layout (byte-based, 256B aligned chunks)
  char* ws = (char*)d_ws;
  size_t off = 0;
  auto allocB = [&](size_t bytes) {
    void* p = ws + off;
    off += ((bytes + 255) & ~(size_t)255);
    return p;
  };
  float* dinv = (float*)allocB((size_t)N * 4);
  int* rowptr = (int*)allocB(((size_t)N + 1) * 4);
  unsigned* bbase = (unsigned*)allocB(257 * 4);
  unsigned* bcur = (unsigned*)allocB(256 * 4);
  unsigned* bhist = (unsigned*)allocB((size_t)nbC * 256 * 4);
  unsigned* packed = (unsigned*)allocB((size_t)E * 4);
  unsigned short* esrc = (unsigned short*)allocB((size_t)E * 2);
  _Float16* xh = (_Float16*)allocB((size_t)N * F * 2);  // x f16 table
  // +64 row padding so tail-block staging reads/writes stay in-bounds
  _Float16* agg = (_Float16*)allocB((size_t)(N + 64) * F * 2);
  _Float16* w1t = (_Float16*)allocB((size_t)F * HID * 2);
  _Float16* w2t = (_Float16*)allocB((size_t)HID * F * 2);
  // h2 aliases agg: fused GEMM reads/writes only its own 64-row tile
  _Float16* h2 = agg;

  int n4 = N * F / 4;
  int nbPrep = nbC + 256 + (n4 + 255) / 256;

  k_prep<<<nbPrep, 256, 0, stream>>>(dst, bhist, W1, W2, x, w1t, w2t, xh,
                                     E, nbC, n4);
  k_bscan<<<1, 256, 0, stream>>>(bhist, nbC, bbase, bcur, rowptr, P, N, E);
  k_binscat<<<nbC, 256, 0, stream>>>(src, dst, bhist, bcur, packed, E);
  k_bcsr<<<P, 256, 0, stream>>>(packed, bbase, dinv, rowptr, esrc, N);

  int nbAgg = (N + 15) / 16;
  int mb = (N + 63) / 64;

  // layer 1 gather, then fused GEMM1+GEMM2 (z1 in LDS), then layer 2 gather
  k_agg1<<<nbAgg, 256, 0, stream>>>(rowptr, esrc, dinv, xh, agg, N);
  k_fgemm<<<mb, 256, 0, stream>>>(agg, w1t, b1, w2t, h2, N);
  k_agg_out<<<nbAgg, 256, 0, stream>>>(rowptr, esrc, dinv, h2, b2, out, N);
}